// Round 17
// baseline (817.106 us; speedup 1.0000x reference)
//
#include <hip/hip_runtime.h>
#include <hip/hip_bf16.h>
#include <math.h>

// ---------------------------------------------------------------------------
// R17: conv3t<1056> -> z-split-3 variant k_c3z3 (3 blocks/CU, no aN dbuf,
//      VGPR-lean). bnstats2/bntr templated on slab count (3 main / 2 res).
//      Res convs keep the proven z2 template. Everything else = R16.
// ---------------------------------------------------------------------------

namespace {

constexpr int S_ = 32, B_ = 128, H_ = 1024, P_ = 196, OC_ = 128;
constexpr int NE = B_ * OC_ * P_;        // elems of a [B][128][196] slab
constexpr int KC = 44;                   // LSTM K chunks: 12 x + 32 h

typedef __attribute__((ext_vector_type(8))) short short8v;
typedef __attribute__((ext_vector_type(4))) short short4v;
typedef __attribute__((ext_vector_type(4))) float f32x4;
#define MFMA16(a, b, c) __builtin_amdgcn_mfma_f32_16x16x32_bf16((a), (b), (c), 0, 0, 0)

__device__ __forceinline__ float sigm(float x){ return 1.0f/(1.0f + expf(-x)); }
__device__ __forceinline__ float c0f(int p){ return ((float)p/14.0f - 7.0f)/7.0f; }
__device__ __forceinline__ float c1f(int p){ return ((float)(p%14) - 7.0f)/7.0f; }
__device__ __forceinline__ unsigned short f2bf(float x){
  __hip_bfloat16 h = __float2bfloat16(x);
  return *reinterpret_cast<unsigned short*>(&h);
}
__device__ __forceinline__ float bf2f(unsigned short u){
  unsigned v = ((unsigned)u) << 16;
  union { unsigned u; float f; } c; c.u = v; return c.f;
}

// ---------------- LSTM weights -> gate-pair fragment pack ---------------------
__global__ void k_packW2(const float* __restrict__ wihf, const float* __restrict__ whhf,
                         const float* __restrict__ wihb, const float* __restrict__ whhb,
                         unsigned short* __restrict__ pk){
  int i = blockIdx.x*256 + threadIdx.x;
  if (i >= 2*32*4*2*KC*64) return;
  const int lane = i & 63;
  int t = i >> 6;
  const int kc = t % KC; t /= KC;
  const int pair = t % 2; t /= 2;
  const int w = t % 4; t /= 4;
  const int uslab = t % 32; t /= 32;
  const int dir = t;
  const int lr = lane & 15, lk = lane >> 4;
  const int row = (pair*2 + (lr >> 3))*1024 + uslab*32 + w*8 + (lr & 7);
  unsigned short v[8];
  if (kc < 12){
    const float* src = dir ? wihb : wihf;
    #pragma unroll
    for (int j = 0; j < 8; ++j){
      int k = kc*32 + lk*8 + j;
      v[j] = (k < 300) ? f2bf(src[(size_t)row*300 + k]) : (unsigned short)0;
    }
  } else {
    const float* src = dir ? whhb : whhf;
    #pragma unroll
    for (int j = 0; j < 8; ++j)
      v[j] = f2bf(src[(size_t)row*1024 + (kc-12)*32 + lk*8 + j]);
  }
  unsigned short* dst = pk + (size_t)i*8;
  #pragma unroll
  for (int j = 0; j < 8; ++j) dst[j] = v[j];
}

// ---------------- embedding -> fragment-packed px -----------------------------
__global__ void k_embed_px(const int* __restrict__ que, const float* __restrict__ emb,
                           unsigned short* __restrict__ px){
  int i = blockIdx.x*256 + threadIdx.x;
  if (i >= 32*8*12*64) return;
  const int lane = i & 63;
  int t2 = i >> 6;
  const int kc = t2 % 12; t2 /= 12;
  const int mgrp = t2 % 8; t2 /= 8;
  const int t = t2;
  const int b = mgrp*16 + (lane & 15);
  const int tok = que[b*S_ + t];
  const int k0 = kc*32 + (lane >> 4)*8;
  unsigned short* dst = px + (size_t)i*8;
  #pragma unroll
  for (int j = 0; j < 8; ++j){
    int k = k0 + j;
    dst[j] = (tok == 0 || k >= 300) ? (unsigned short)0 : f2bf(emb[(size_t)tok*300 + k]);
  }
}

// ---------------- x-part GEMM for all steps -> xg (fragment-order bf16) -------
__launch_bounds__(256, 4)
__global__ void k_xg(const unsigned short* __restrict__ px,
                     const unsigned short* __restrict__ pkW2,
                     unsigned short* __restrict__ xg){
  const int dir = blockIdx.x >> 5, uslab = blockIdx.x & 31;
  const int mslab = blockIdx.y;
  const int xs = blockIdx.z;
  const int tid = threadIdx.x, w = tid >> 6, lane = tid & 63;

  const unsigned short* pb = pkW2 + ((((size_t)(dir*32 + uslab)*4 + w)*2)*KC*64 + lane)*8;
  const size_t pbPair = (size_t)KC*512;
  const unsigned short* pax = px + (((size_t)(xs*8 + mslab*2)*12)*64 + lane)*8;
  const size_t paxRf = (size_t)12*512;

  f32x4 a00{0,0,0,0}, a01{0,0,0,0}, a10{0,0,0,0}, a11{0,0,0,0};
  #pragma unroll 4
  for (int ch = 0; ch < 12; ++ch){
    short8v a0 = *(const short8v*)(pax + (size_t)ch*512);
    short8v a1 = *(const short8v*)(pax + paxRf + (size_t)ch*512);
    short8v b0 = *(const short8v*)(pb + (size_t)ch*512);
    short8v b1 = *(const short8v*)(pb + pbPair + (size_t)ch*512);
    a00 = MFMA16(a0, b0, a00); a01 = MFMA16(a0, b1, a01);
    a10 = MFMA16(a1, b0, a10); a11 = MFMA16(a1, b1, a11);
  }

  const size_t rid = (((size_t)((xs*2 + dir)*4 + mslab)*32 + uslab)*4 + w);
  unsigned short* rec = xg + rid*1024;
  f32x4 accs[4] = {a00, a01, a10, a11};
  #pragma unroll
  for (int r = 0; r < 2; ++r)
    #pragma unroll
    for (int p = 0; p < 2; ++p){
      f32x4 v = accs[r*2 + p];
      short4v sv;
      #pragma unroll
      for (int j = 0; j < 4; ++j) sv[j] = (short)f2bf(v[j]);
      *(short4v*)(rec + ((p*2 + r)*64 + lane)*4) = sv;
    }
}

// ---------------- conv3 weights -> fragment-order pack ------------------------
__global__ void k_packC(const float* __restrict__ w, unsigned short* __restrict__ pk,
                        int cin, int T){
  int i = blockIdx.x*256 + threadIdx.x;
  if (i >= 9*8*T*64) return;
  const int lane = i & 63;
  int t = i >> 6;
  const int kc = t % T; t /= T;
  const int ot = t % 8; t /= 8;
  const int s = t;
  const int oc = ot*16 + (lane & 15);
  const int c0 = kc*32 + (lane >> 4)*8;
  unsigned short* dst = pk + (((size_t)(s*8 + ot)*T + kc)*64 + lane)*8;
  #pragma unroll
  for (int j = 0; j < 8; ++j){
    int c = c0 + j;
    dst[j] = (c < cin) ? f2bf(w[((size_t)oc*cin + c)*9 + s]) : (unsigned short)0;
  }
}

// ---------------- 1x1 weights [128][cin] -> fragment-order pack ---------------
__global__ void k_packG(const float* __restrict__ w, unsigned short* __restrict__ pk,
                        int cin, int T){
  int i = blockIdx.x*256 + threadIdx.x;
  if (i >= 8*T*64) return;
  const int lane = i & 63;
  int t = i >> 6;
  const int kc = t % T; t /= T;
  const int ot = t;
  const int oc = ot*16 + (lane & 15);
  const int c0 = kc*32 + (lane >> 4)*8;
  unsigned short* dst = pk + (((size_t)(ot*T + kc))*64 + lane)*8;
  #pragma unroll
  for (int j = 0; j < 8; ++j){
    int c = c0 + j;
    dst[j] = (c < cin) ? f2bf(w[(size_t)oc*cin + c]) : (unsigned short)0;
  }
}

__global__ void k_bias2(const float* __restrict__ bif, const float* __restrict__ bhf,
                        const float* __restrict__ bib, const float* __restrict__ bhb,
                        float* __restrict__ out){
  int i = blockIdx.x*256 + threadIdx.x;
  if (i >= 8192) return;
  out[i] = (i < 4096) ? (bif[i] + bhf[i]) : (bib[i-4096] + bhb[i-4096]);
}

// ---------------- vTb coord channels (written once) ---------------------------
__global__ void k_coordT(unsigned short* __restrict__ outT){
  int i = blockIdx.x*256 + threadIdx.x;
  if (i >= 128*196*32) return;
  int c2 = i & 31; int t = i >> 5; int p = t % 196; int b = t / 196;
  float v = (c2 == 0) ? c0f(p) : (c2 == 1) ? c1f(p) : 0.f;
  outT[((size_t)b*196 + p)*160 + 128 + c2] = f2bf(v);
}

// ---------------- one LSTM step (v11: M=16 rows, 4 blocks/CU) -----------------
__launch_bounds__(256, 4)
__global__ void k_step11(const unsigned short* __restrict__ xg,
                         const unsigned short* __restrict__ pkW2,
                         const float* __restrict__ bias2,
                         const unsigned short* __restrict__ hin,
                         unsigned short* __restrict__ hout,
                         float* __restrict__ cst, float* __restrict__ Q, int s){
  const int dir   = blockIdx.x >> 5;
  const int uslab = blockIdx.x & 31;
  const int mslab = blockIdx.y;          // 0..7, 16 rows each
  const int m0g   = mslab*16;
  const int tid = threadIdx.x, w = tid >> 6, lane = tid & 63;
  const int lr = lane & 15, lk = lane >> 4;
  const int xs = dir ? (S_-1-s) : s;

  __shared__ unsigned short tA[16][1032];

  {
    const int r = tid >> 4, sg = tid & 15;
    const unsigned short* hr = hin + ((size_t)dir*B_ + m0g + r)*H_;
    #pragma unroll
    for (int q = 0; q < 8; ++q){
      const int u = sg + q*16;
      *(short8v*)&tA[r][u*8] = *(const short8v*)(hr + u*8);
    }
  }

  const size_t rid = (((size_t)((xs*2 + dir)*4 + (mslab >> 1))*32 + uslab)*4 + w);
  const int rf = mslab & 1;
  const unsigned short* rec = xg + rid*1024;
  f32x4 a00, a01;
  {
    short4v s0 = *(const short4v*)(rec + ((0*2 + rf)*64 + lane)*4);
    short4v s1 = *(const short4v*)(rec + ((1*2 + rf)*64 + lane)*4);
    #pragma unroll
    for (int j = 0; j < 4; ++j){
      a00[j] = bf2f((unsigned short)s0[j]);
      a01[j] = bf2f((unsigned short)s1[j]);
    }
  }

  const unsigned short* pb = pkW2 + ((((size_t)(dir*32 + uslab)*4 + w)*2)*KC*64 + lane)*8;
  const size_t pbPair = (size_t)KC*512;

  __syncthreads();

  #pragma unroll 8
  for (int ch = 0; ch < 32; ++ch){
    const int ka = ch*32 + lk*8;
    short8v a0 = *(short8v*)&tA[lr][ka];
    short8v b0 = *(const short8v*)(pb + (size_t)(12 + ch)*512);
    short8v b1 = *(const short8v*)(pb + pbPair + (size_t)(12 + ch)*512);
    a00 = MFMA16(a0, b0, a00);
    a01 = MFMA16(a0, b1, a01);
  }

  const int ug = uslab*32 + w*8 + (lr & 7);
  const float* bb = bias2 + (size_t)dir*4096;
  const float bi = bb[ug], bfv = bb[1024+ug], bg = bb[2048+ug], bo = bb[3072+ug];
  float* cc = cst + (size_t)dir*B_*H_;
  unsigned short* ho = hout + (size_t)dir*B_*H_;
  const int jbase = (lr & 8) ? 2 : 0;

  float p0[4], p1[4];
  #pragma unroll
  for (int j = 0; j < 4; ++j){
    p0[j] = __shfl_xor(a00[j], 8, 64);
    p1[j] = __shfl_xor(a01[j], 8, 64);
  }
  #pragma unroll
  for (int q = 0; q < 2; ++q){
    const int jj = jbase + q;
    float gi, gf, gg, go;
    if (lr & 8){ gi = p0[jj]; gf = a00[jj]; gg = p1[jj]; go = a01[jj]; }
    else       { gi = a00[jj]; gf = p0[jj]; gg = a01[jj]; go = p1[jj]; }
    gi += bi; gf += bfv; gg += bg; go += bo;
    const int m = m0g + lk*4 + jj;
    const size_t coff = (size_t)m*H_ + ug;
    float cold = cc[coff];
    float cn = sigm(gf)*cold + sigm(gi)*tanhf(gg);
    float hn = sigm(go)*tanhf(cn);
    cc[coff] = cn;
    ho[coff] = f2bf(hn);
    Q[((size_t)xs*B_ + m)*2048 + dir*1024 + ug] = hn;
  }
}

// ---------------- qenc L2-normalize (in-place) + enc --------------------------
__global__ void k_qnorm(float* __restrict__ Q, float* __restrict__ enc){
  int sb = blockIdx.x;
  int s = sb >> 7, b = sb & 127;
  float* row = Q + (size_t)sb*2048;
  int tid = threadIdx.x;
  float v[8]; float ss = 0.f;
  #pragma unroll
  for (int i = 0; i < 8; ++i){ v[i] = row[tid*8+i]; ss += v[i]*v[i]; }
  __shared__ float red[256];
  red[tid] = ss; __syncthreads();
  for (int st = 128; st; st >>= 1){
    if (tid < st) red[tid] += red[tid+st];
    __syncthreads();
  }
  float inv = 1.0f / fmaxf(sqrtf(red[0]), 1e-12f);
  #pragma unroll
  for (int i = 0; i < 8; ++i){
    float q = v[i]*inv;
    row[tid*8+i] = q;
    if (s == S_-1) enc[(size_t)b*2048 + tid*8 + i] = q;
  }
}

// ---------------- per-pixel channel sumsq of img ------------------------------
__global__ void k_sqpart(const float* __restrict__ img, float* __restrict__ part){
  int b = blockIdx.x, cq = blockIdx.y;
  int t = threadIdx.x;
  if (t >= P_) return;
  const float* base = img + ((size_t)b*1024 + cq*256)*P_ + t;
  float s = 0.f;
  #pragma unroll 4
  for (int c = 0; c < 256; ++c){ float v = base[c*P_]; s += v*v; }
  part[((size_t)b*4 + cq)*P_ + t] = s;
}

__global__ void k_invnorm(const float* __restrict__ part, float* __restrict__ inv){
  int i = blockIdx.x*256 + threadIdx.x;
  if (i >= B_*P_) return;
  int b = i / P_, p = i % P_;
  float s = part[(b*4+0)*P_+p] + part[(b*4+1)*P_+p]
          + part[(b*4+2)*P_+p] + part[(b*4+3)*P_+p];
  inv[i] = 1.0f / fmaxf(sqrtf(s), 1e-12f);
}

// ---------------- img -> imgT[b][196][1056] bf16 (invnorm+coords+pad) ---------
__global__ void k_mkimgT(const float* __restrict__ img, const float* __restrict__ invn,
                         unsigned short* __restrict__ imgT){
  const int b = blockIdx.x, cg = blockIdx.y;
  const int tid = threadIdx.x;
  unsigned short* dstB = imgT + (size_t)b*196*1056;
  if (cg == 8){
    for (int i = tid; i < 196*32; i += 256){
      int p = i >> 5, cc = i & 31;
      float v = (cc == 0) ? c0f(p) : (cc == 1) ? c1f(p) : 0.f;
      dstB[(size_t)p*1056 + 1024 + cc] = f2bf(v);
    }
    return;
  }
  __shared__ unsigned short tt[196][136];
  __shared__ float sInv[200];
  for (int i = tid; i < 196; i += 256) sInv[i] = invn[b*196 + i];
  __syncthreads();
  const int c0 = cg*128;
  const float* srcB = img + ((size_t)b*1024 + c0)*196;
  for (int i = tid; i < 128*49; i += 256){
    int c = i / 49, p4 = i - (i/49)*49;
    float4 v = *(const float4*)(srcB + (size_t)c*196 + p4*4);
    int p = p4*4;
    tt[p+0][c] = f2bf(v.x * sInv[p+0]);
    tt[p+1][c] = f2bf(v.y * sInv[p+1]);
    tt[p+2][c] = f2bf(v.z * sInv[p+2]);
    tt[p+3][c] = f2bf(v.w * sInv[p+3]);
  }
  __syncthreads();
  for (int i = tid; i < 196*16; i += 256){
    int p = i >> 4, g = i & 15;
    *(short8v*)(dstB + (size_t)p*1056 + c0 + g*8) = *(short8v*)&tt[p][g*8];
  }
}

// ---------------- shared staging helper ---------------------------------------
template<int CPAD>
__device__ __forceinline__ void stage3t(unsigned short (*__restrict__ tile)[40],
                                        const unsigned short* __restrict__ src,
                                        int c0, int r0, int tid){
  for (int i = tid; i < 10*14*4; i += 256){
    int t = i / 56, rem = i - t*56, gx = rem >> 2, seg = rem & 3;
    int gy = r0 - 1 + t;
    if ((unsigned)gy < 14u){
      short8v v = *(const short8v*)(src + (size_t)(gy*14+gx)*CPAD + c0 + seg*8);
      *(short8v*)&tile[t*16 + gx + 1][seg*8] = v;
    }
  }
}

// ---------------- 3x3 conv, z-split-3 VGPR-lean variant (main conv) -----------
// grid (128 b, 2 n, 3 z); 3 blocks/CU. aC loaded per (chunk,dy); no aN.
template<int CPAD>
__launch_bounds__(256, 3)
__global__ void k_c3z3(const unsigned short* __restrict__ srcT,
                       const unsigned short* __restrict__ wPk,
                       const float* __restrict__ bias,
                       float* __restrict__ out){
  constexpr int T = CPAD / 32;
  const int b = blockIdx.x, n = blockIdx.y, z = blockIdx.z;
  const int r0 = n ? 6 : 0;
  const int chBeg = (z*T)/3, chEnd = ((z+1)*T)/3;
  const int tid = threadIdx.x, wave = tid >> 6, lane = tid & 63;
  const int lr = lane & 15, lk = lane >> 4;
  const int wfM = wave >> 1, wfN = wave & 1;
  const unsigned short* src = srcT + (size_t)b*196*CPAD;

  __shared__ unsigned short tile[2][164][40];

  for (int i = tid; i < 1640; i += 256)
    ((short8v*)&tile[0][0][0])[i] = short8v{0,0,0,0,0,0,0,0};
  __syncthreads();
  stage3t<CPAD>(tile[0], src, chBeg*32, r0, tid);
  __syncthreads();

  f32x4 acc[4][4];
  #pragma unroll
  for (int i = 0; i < 4; ++i)
    #pragma unroll
    for (int j = 0; j < 4; ++j) acc[i][j] = f32x4{0,0,0,0};

  for (int ch = chBeg; ch < chEnd; ++ch){
    const int cur = (ch - chBeg) & 1;
    #pragma unroll
    for (int dy = 0; dy < 3; ++dy){
      short8v aC[12];
      #pragma unroll
      for (int dx = 0; dx < 3; ++dx)
        #pragma unroll
        for (int rf = 0; rf < 4; ++rf)
          aC[dx*4+rf] = *(const short8v*)(wPk + ((((size_t)(dy*3+dx)*8 + wfM*4 + rf)*T
                                                  + ch)*64 + lane)*8);
      #pragma unroll
      for (int dx = 0; dx < 3; ++dx){
        const int dlt = dy*16 + dx;
        #pragma unroll
        for (int cf = 0; cf < 4; ++cf){
          short8v bf = *(short8v*)&tile[cur][wfN*64 + cf*16 + lr + dlt][lk*8];
          #pragma unroll
          for (int rf = 0; rf < 4; ++rf)
            acc[rf][cf] = MFMA16(aC[dx*4+rf], bf, acc[rf][cf]);
        }
      }
      if (dy == 0 && ch + 1 < chEnd)
        stage3t<CPAD>(tile[cur^1], src, (ch+1)*32, r0, tid);
    }
    __syncthreads();
  }

  #pragma unroll
  for (int rf = 0; rf < 4; ++rf){
    #pragma unroll
    for (int j = 0; j < 4; ++j){
      const int oc = wfM*64 + rf*16 + lk*4 + j;
      const float bz = z ? 0.f : bias[oc];
      #pragma unroll
      for (int cf = 0; cf < 4; ++cf){
        const int pos = wfN*64 + cf*16 + lr;
        const int py = r0 + (pos >> 4), px = pos & 15;
        const bool rowok = n ? (py >= 8) : true;
        if (rowok && px < 14)
          out[(size_t)z*NE + ((size_t)b*OC_ + oc)*P_ + py*14 + px] = acc[rf][cf][j] + bz;
      }
    }
  }
}

// ---------------- 3x3 conv via MFMA (proven z2 template, res convs) -----------
template<int CPAD>
__launch_bounds__(256, 2)
__global__ void k_conv3t(const unsigned short* __restrict__ srcT,
                         const unsigned short* __restrict__ wPk,
                         const float* __restrict__ bias,
                         float* __restrict__ out){
  constexpr int T = CPAD / 32;
  const int b = blockIdx.x, n = blockIdx.y, z = blockIdx.z;
  const int r0 = n ? 6 : 0;
  const int chBeg = z ? T/2 : 0, chEnd = z ? T : T/2;
  const int tid = threadIdx.x, wave = tid >> 6, lane = tid & 63;
  const int lr = lane & 15, lk = lane >> 4;
  const int wfM = wave >> 1, wfN = wave & 1;
  const unsigned short* src = srcT + (size_t)b*196*CPAD;

  __shared__ unsigned short tile[2][164][40];

  for (int i = tid; i < 1640; i += 256)
    ((short8v*)&tile[0][0][0])[i] = short8v{0,0,0,0,0,0,0,0};
  __syncthreads();
  stage3t<CPAD>(tile[0], src, chBeg*32, r0, tid);
  __syncthreads();

  f32x4 acc[4][4];
  #pragma unroll
  for (int i = 0; i < 4; ++i)
    #pragma unroll
    for (int j = 0; j < 4; ++j) acc[i][j] = f32x4{0,0,0,0};

  short8v aC[12], aN[12];
  #pragma unroll
  for (int dx = 0; dx < 3; ++dx)
    #pragma unroll
    for (int rf = 0; rf < 4; ++rf)
      aC[dx*4+rf] = *(const short8v*)(wPk + ((((size_t)dx*8 + wfM*4 + rf)*T + chBeg)*64
                                             + lane)*8);

  for (int ch = chBeg; ch < chEnd; ++ch){
    const int cur = (ch - chBeg) & 1;
    #pragma unroll
    for (int dy = 0; dy < 3; ++dy){
      const int ndy = (dy < 2) ? dy + 1 : 0;
      const int nch = (dy < 2) ? ch : ch + 1;
      const bool hasN = nch < chEnd;
      if (hasN){
        #pragma unroll
        for (int dx = 0; dx < 3; ++dx)
          #pragma unroll
          for (int rf = 0; rf < 4; ++rf)
            aN[dx*4+rf] = *(const short8v*)(wPk + ((((size_t)(ndy*3+dx)*8 + wfM*4 + rf)*T
                                                    + nch)*64 + lane)*8);
      }
      #pragma unroll
      for (int dx = 0; dx < 3; ++dx){
        const int dlt = dy*16 + dx;
        #pragma unroll
        for (int cf = 0; cf < 4; ++cf){
          short8v bf = *(short8v*)&tile[cur][wfN*64 + cf*16 + lr + dlt][lk*8];
          #pragma unroll
          for (int rf = 0; rf < 4; ++rf)
            acc[rf][cf] = MFMA16(aC[dx*4+rf], bf, acc[rf][cf]);
        }
      }
      if (dy == 0 && ch + 1 < chEnd)
        stage3t<CPAD>(tile[cur^1], src, (ch+1)*32, r0, tid);
      if (hasN){
        #pragma unroll
        for (int q = 0; q < 12; ++q) aC[q] = aN[q];
      }
    }
    __syncthreads();
  }

  #pragma unroll
  for (int rf = 0; rf < 4; ++rf){
    #pragma unroll
    for (int j = 0; j < 4; ++j){
      const int oc = wfM*64 + rf*16 + lk*4 + j;
      const float bz = z ? 0.f : bias[oc];
      #pragma unroll
      for (int cf = 0; cf < 4; ++cf){
        const int pos = wfN*64 + cf*16 + lr;
        const int py = r0 + (pos >> 4), px = pos & 15;
        const bool rowok = n ? (py >= 8) : true;
        if (rowok && px < 14)
          out[(size_t)z*NE + ((size_t)b*OC_ + oc)*P_ + py*14 + px] = acc[rf][cf][j] + bz;
      }
    }
  }
}

// ---------------- BN stats: phase 1 (partials over NS slabs) ------------------
template<int NS>
__global__ void k_bnstats2(const float* __restrict__ t, float* __restrict__ bpart){
  const int o = blockIdx.x, part = blockIdx.y;
  const int tid = threadIdx.x;
  float s = 0.f, s2 = 0.f;
  for (int i = tid; i < 16*196; i += 256){
    int b = part*16 + i/196, p = i - (i/196)*196;
    size_t off = ((size_t)b*OC_ + o)*P_ + p;
    float v = 0.f;
    #pragma unroll
    for (int q = 0; q < NS; ++q) v += t[off + (size_t)q*NE];
    s += v; s2 += v*v;
  }
  __shared__ float r1[256], r2[256];
  r1[tid] = s; r2[tid] = s2; __syncthreads();
  for (int st = 128; st; st >>= 1){
    if (tid < st){ r1[tid] += r1[tid+st]; r2[tid] += r2[tid+st]; }
    __syncthreads();
  }
  if (tid == 0){
    bpart[(o*8 + part)*2]     = r1[0];
    bpart[(o*8 + part)*2 + 1] = r2[0];
  }
}

// ---------------- BN stats: phase 2 (finalize) --------------------------------
__global__ void k_bnfin(const float* __restrict__ bpart, float* __restrict__ stats){
  int o = threadIdx.x;
  if (o >= 128) return;
  float s = 0.f, s2 = 0.f;
  #pragma unroll
  for (int q = 0; q < 8; ++q){
    s  += bpart[(o*8 + q)*2];
    s2 += bpart[(o*8 + q)*2 + 1];
  }
  float n = (float)(B_*P_);
  float m = s / n;
  float var = s2 / n - m*m;
  stats[o*2]   = m;
  stats[o*2+1] = rsqrtf(var + 1e-5f);
}

// ---------------- BN apply + relu (+add), NS-slab sum -------------------------
template<bool ADD, bool FINAL, int NS>
__global__ void k_bntr(const float* __restrict__ t, const float* __restrict__ stats,
                       const float* __restrict__ g, const float* __restrict__ bb,
                       const float* __restrict__ addsrc,
                       float* __restrict__ outF, unsigned short* __restrict__ outT){
  const int b = blockIdx.x, seg = blockIdx.y, tid = threadIdx.x;
  for (int i = tid; i < 16*196; i += 256){
    int c = seg*16 + i/196, p = i - (i/196)*196;
    size_t off = ((size_t)b*OC_ + c)*P_ + p;
    float x = 0.f;
    #pragma unroll
    for (int q = 0; q < NS; ++q) x += t[off + (size_t)q*NE];
    float v = g[c]*(x - stats[c*2])*stats[c*2+1] + bb[c];
    v = fmaxf(v, 0.f);
    if (ADD) v += addsrc[off];
    if (FINAL) outF[off] = v;
    else       outT[((size_t)b*P_ + p)*160 + c] = f2bf(v);
  }
}

// ---------------- 1x1 conv via MFMA -------------------------------------------
__launch_bounds__(256, 2)
__global__ void k_c1m(const unsigned short* __restrict__ vT,
                      const unsigned short* __restrict__ pk,
                      const float* __restrict__ bias,
                      float* __restrict__ out, unsigned short* __restrict__ outT){
  const int b = blockIdx.x, n = blockIdx.y;
  const int pBeg = n ? 112 : 0;
  const int nCF = n ? 6 : 7;
  const int tid = threadIdx.x, wave = tid >> 6, lane = tid & 63;
  const int lr = lane & 15, lk = lane >> 4;

  __shared__ unsigned short tile[112][164];

  for (int i = tid; i < 112*20; i += 256){
    int r = i / 20, seg = i - r*20;
    int p = pBeg + r;
    short8v v = short8v{0,0,0,0,0,0,0,0};
    if (p < 196 && r < nCF*16)
      v = *(const short8v*)(vT + ((size_t)b*P_ + p)*160 + seg*8);
    *(short8v*)&tile[r][seg*8] = v;
  }
  __syncthreads();

  f32x4 acc[2][7];
  #pragma unroll
  for (int i = 0; i < 2; ++i)
    #pragma unroll
    for (int j = 0; j < 7; ++j) acc[i][j] = f32x4{0,0,0,0};

  #pragma unroll
  for (int kc = 0; kc < 5; ++kc){
    short8v a0 = *(const short8v*)(pk + (((size_t)(wave*2 + 0)*5 + kc)*64 + lane)*8);
    short8v a1 = *(const short8v*)(pk + (((size_t)(wave*2 + 1)*5 + kc)*64 + lane)*8);
    #pragma unroll
    for (int cf = 0; cf < 7; ++cf){
      if (cf < nCF){
        short8v bf = *(short8v*)&tile[cf*16 + lr][kc*32 + lk*8];
        acc[0][cf] = MFMA16(a0, bf, acc[0][cf]);
        acc[1][cf] = MFMA16(a1, bf, acc[1][cf]);
      }
    }
  }

  #pragma unroll
  for (int rf = 0; rf < 2; ++rf){
    const int ocBase = wave*32 + rf*16 + lk*4;
    #pragma unroll
    for (int cf = 0; cf < 7; ++cf){
      if (cf < nCF){
        const int pos = pBeg + cf*16 + lr;
        if (pos < 196){
          short4v sv;
          #pragma unroll
          for (int j = 0; j < 4; ++j){
            const int oc = ocBase + j;
            float v = fmaxf(acc[rf][cf][j] + bias[oc], 0.f);
            out[((size_t)b*OC_ + oc)*P_ + pos] = v;
            sv[j] = (short)f2bf(v);
          }
          *(short4v*)(outT + ((size_t)b*P_ + pos)*128 + ocBase) = sv;
        }
      }
    }
  }
}

} // namespace

// ---------------------------------------------------------------------------
extern "C" void kernel_launch(void* const* d_in, const int* in_sizes, int n_in,
                              void* d_out, int out_size, void* d_ws, size_t ws_size,
                              hipStream_t stream){
  (void)in_sizes; (void)n_in; (void)out_size; (void)ws_size;
  const int*   que  = (const int*)  d_in[0];
  const float* img  = (const float*)d_in[1];
  const float* emb  = (const float*)d_in[2];
  const float* wihf = (const float*)d_in[3];
  const float* whhf = (const float*)d_in[4];
  const float* bihf = (const float*)d_in[5];
  const float* bhhf = (const float*)d_in[6];
  const float* wihb = (const float*)d_in[7];
  const float* whhb = (const float*)d_in[8];
  const float* bihb = (const float*)d_in[9];
  const float* bhhb = (const float*)d_in[10];
  const float* convw = (const float*)d_in[11];
  const float* convb = (const float*)d_in[12];
  const float* bng  = (const float*)d_in[13];
  const float* bnb  = (const float*)d_in[14];
  const float* r1c1w = (const float*)d_in[15];
  const float* r1c1b = (const float*)d_in[16];
  const float* r1c2w = (const float*)d_in[17];
  const float* r1c2b = (const float*)d_in[18];
  const float* r1bng = (const float*)d_in[19];
  const float* r1bnb = (const float*)d_in[20];
  const float* r2c1w = (const float*)d_in[21];
  const float* r2c1b = (const float*)d_in[22];
  const float* r2c2w = (const float*)d_in[23];
  const float* r2c2b = (const float*)d_in[24];
  const float* r2bng = (const float*)d_in[25];
  const float* r2bnb = (const float*)d_in[26];

  float* out  = (float*)d_out;
  float* enc  = out;                        // 128*2048
  float* Q    = out + 262144;               // 32*128*2048
  float* vout = out + 262144 + 8388608;     // 128*128*196

  // ------ workspace layout (f32 units) ----------------------------------------
  float* ws = (float*)d_ws;
  unsigned short* px   = (unsigned short*)ws;                  // 32*8*12*512 bf16
  unsigned short* pkW2 = (unsigned short*)(ws + 786432);       // 2*32*4*2*44*512 bf16
  float* bias2 = ws + 6553600;                                 // 2*4096
  unsigned short* hstate = (unsigned short*)(ws + 6561792);    // 2par*2dir*128*1024 bf16
  float* cstate = ws + 6823936;                                // 2*128*1024
  float* part   = ws + 7086080;                                // 128*4*196
  float* invn   = ws + 7186432;                                // 128*196
  float* stats  = ws + 7211520;                                // 256
  float* bpart  = ws + 7211776;                                // 128*8*2
  unsigned short* pkC  = (unsigned short*)(ws + 7213824);      // 9*8*33*512 bf16
  unsigned short* pkR1 = (unsigned short*)(ws + 7822080);      // 9*8*4*512 bf16
  unsigned short* pkR2 = (unsigned short*)(ws + 7895808);      // 9*8*4*512 bf16
  unsigned short* pk1  = (unsigned short*)(ws + 7969536);      // 8*5*512 bf16
  unsigned short* pk2  = (unsigned short*)(ws + 7979776);      // 8*5*512 bf16
  float* U = ws + 7990016;                                     // union region
  // LSTM phase: xg = 32768 records x 1024 bf16 = 16.8M floats
  unsigned short* xg = (unsigned short*)U;
  // image phase (bufB/convOut/imgT written only after LSTM finishes):
  float* bufB = U;                                             // NE (v1 f32)
  float* convOut = U + NE;                                     // up to 3*NE partial slabs
  unsigned short* imgT = (unsigned short*)(U + 4*(size_t)NE);  // 128*196*1056
  unsigned short* vTb  = (unsigned short*)(U + 4*(size_t)NE + 13246464);
  unsigned short* v1T  = (unsigned short*)(U + 4*(size_t)NE + 13246464 + 2007040);

  hipMemsetAsync(hstate, 0, (size_t)(262144 + 262144)*sizeof(float), stream);

  // ------ packing / conversions ------------------------------------------------
  k_packW2<<<(2*32*4*2*KC*64 + 255)/256, 256, 0, stream>>>(wihf, whhf, wihb, whhb, pkW2);
  k_embed_px<<<(32*8*12*64 + 255)/256, 256, 0, stream>>>(que, emb, px);
  k_packC<<<(9*8*33*64 + 255)/256, 256, 0, stream>>>(convw, pkC, 1026, 33);
  k_packC<<<(9*8*4*64 + 255)/256, 256, 0, stream>>>(r1c2w, pkR1, 128, 4);
  k_packC<<<(9*8*4*64 + 255)/256, 256, 0, stream>>>(r2c2w, pkR2, 128, 4);
  k_packG<<<(8*5*64 + 255)/256, 256, 0, stream>>>(r1c1w, pk1, 130, 5);
  k_packG<<<(8*5*64 + 255)/256, 256, 0, stream>>>(r2c1w, pk2, 130, 5);
  k_bias2<<<32, 256, 0, stream>>>(bihf, bhhf, bihb, bhhb, bias2);
  k_coordT<<<(128*196*32 + 255)/256, 256, 0, stream>>>(vTb);   // vTb doesn't alias xg

  // ------ x-part GEMM for all steps (one wide launch) --------------------------
  k_xg<<<dim3(64,4,32), 256, 0, stream>>>(px, pkW2, xg);

  // ------ bi-LSTM: 32 h-only step launches (M=16 rows/block) -------------------
  for (int s = 0; s < 32; ++s){
    unsigned short* hin  = hstate + (size_t)(s & 1)*262144;
    unsigned short* hout = hstate + (size_t)((s & 1)^1)*262144;
    k_step11<<<dim3(64,8), 256, 0, stream>>>(xg, pkW2, bias2, hin, hout,
                                             cstate, Q, s);
  }
  k_qnorm<<<4096, 256, 0, stream>>>(Q, enc);

  // ------ image branch (after LSTM: imgT/bufB/convOut alias xg) ---------------
  k_sqpart<<<dim3(128,4), 256, 0, stream>>>(img, part);
  k_invnorm<<<(25088+255)/256, 256, 0, stream>>>(part, invn);
  k_mkimgT<<<dim3(128,9), 256, 0, stream>>>(img, invn, imgT);

  k_c3z3<1056><<<dim3(128,2,3), 256, 0, stream>>>(imgT, pkC, convb, convOut);
  k_bnstats2<3><<<dim3(128,8), 256, 0, stream>>>(convOut, bpart);
  k_bnfin<<<1, 128, 0, stream>>>(bpart, stats);
  k_bntr<false,false,3><<<dim3(128,8), 256, 0, stream>>>(convOut, stats, bng, bnb,
                                                         nullptr, nullptr, vTb);

  // res block 1: vTb -> (bufB f32, v1T) -> convOut -> vTb
  k_c1m<<<dim3(128,2), 256, 0, stream>>>(vTb, pk1, r1c1b, bufB, v1T);
  k_conv3t<128><<<dim3(128,2,2), 256, 0, stream>>>(v1T, pkR1, r1c2b, convOut);
  k_bnstats2<2><<<dim3(128,8), 256, 0, stream>>>(convOut, bpart);
  k_bnfin<<<1, 128, 0, stream>>>(bpart, stats);
  k_bntr<true,false,2><<<dim3(128,8), 256, 0, stream>>>(convOut, stats, r1bng, r1bnb,
                                                        bufB, nullptr, vTb);

  // res block 2: vTb -> (bufB, v1T) -> convOut -> vout
  k_c1m<<<dim3(128,2), 256, 0, stream>>>(vTb, pk2, r2c1b, bufB, v1T);
  k_conv3t<128><<<dim3(128,2,2), 256, 0, stream>>>(v1T, pkR2, r2c2b, convOut);
  k_bnstats2<2><<<dim3(128,8), 256, 0, stream>>>(convOut, bpart);
  k_bnfin<<<1, 128, 0, stream>>>(bpart, stats);
  k_bntr<true,true,2><<<dim3(128,8), 256, 0, stream>>>(convOut, stats, r2bng, r2bnb,
                                                       bufB, vout, nullptr);
}

// Round 18
// 741.173 us; speedup vs baseline: 1.1024x; 1.1024x over previous
//
#include <hip/hip_runtime.h>
#include <hip/hip_bf16.h>
#include <math.h>

// ---------------------------------------------------------------------------
// R18: revert main conv to proven z2 k_conv3t (R17's z3 spilled again:
//      234MB FETCH). Fold bnfin into bntr (inline 8-partial stats reduce,
//      removes 3 single-block launches). Everything else = R16.
// ---------------------------------------------------------------------------

namespace {

constexpr int S_ = 32, B_ = 128, H_ = 1024, P_ = 196, OC_ = 128;
constexpr int NE = B_ * OC_ * P_;        // elems of a [B][128][196] slab
constexpr int KC = 44;                   // LSTM K chunks: 12 x + 32 h

typedef __attribute__((ext_vector_type(8))) short short8v;
typedef __attribute__((ext_vector_type(4))) short short4v;
typedef __attribute__((ext_vector_type(4))) float f32x4;
#define MFMA16(a, b, c) __builtin_amdgcn_mfma_f32_16x16x32_bf16((a), (b), (c), 0, 0, 0)

__device__ __forceinline__ float sigm(float x){ return 1.0f/(1.0f + expf(-x)); }
__device__ __forceinline__ float c0f(int p){ return ((float)p/14.0f - 7.0f)/7.0f; }
__device__ __forceinline__ float c1f(int p){ return ((float)(p%14) - 7.0f)/7.0f; }
__device__ __forceinline__ unsigned short f2bf(float x){
  __hip_bfloat16 h = __float2bfloat16(x);
  return *reinterpret_cast<unsigned short*>(&h);
}
__device__ __forceinline__ float bf2f(unsigned short u){
  unsigned v = ((unsigned)u) << 16;
  union { unsigned u; float f; } c; c.u = v; return c.f;
}

// ---------------- LSTM weights -> gate-pair fragment pack ---------------------
__global__ void k_packW2(const float* __restrict__ wihf, const float* __restrict__ whhf,
                         const float* __restrict__ wihb, const float* __restrict__ whhb,
                         unsigned short* __restrict__ pk){
  int i = blockIdx.x*256 + threadIdx.x;
  if (i >= 2*32*4*2*KC*64) return;
  const int lane = i & 63;
  int t = i >> 6;
  const int kc = t % KC; t /= KC;
  const int pair = t % 2; t /= 2;
  const int w = t % 4; t /= 4;
  const int uslab = t % 32; t /= 32;
  const int dir = t;
  const int lr = lane & 15, lk = lane >> 4;
  const int row = (pair*2 + (lr >> 3))*1024 + uslab*32 + w*8 + (lr & 7);
  unsigned short v[8];
  if (kc < 12){
    const float* src = dir ? wihb : wihf;
    #pragma unroll
    for (int j = 0; j < 8; ++j){
      int k = kc*32 + lk*8 + j;
      v[j] = (k < 300) ? f2bf(src[(size_t)row*300 + k]) : (unsigned short)0;
    }
  } else {
    const float* src = dir ? whhb : whhf;
    #pragma unroll
    for (int j = 0; j < 8; ++j)
      v[j] = f2bf(src[(size_t)row*1024 + (kc-12)*32 + lk*8 + j]);
  }
  unsigned short* dst = pk + (size_t)i*8;
  #pragma unroll
  for (int j = 0; j < 8; ++j) dst[j] = v[j];
}

// ---------------- embedding -> fragment-packed px -----------------------------
__global__ void k_embed_px(const int* __restrict__ que, const float* __restrict__ emb,
                           unsigned short* __restrict__ px){
  int i = blockIdx.x*256 + threadIdx.x;
  if (i >= 32*8*12*64) return;
  const int lane = i & 63;
  int t2 = i >> 6;
  const int kc = t2 % 12; t2 /= 12;
  const int mgrp = t2 % 8; t2 /= 8;
  const int t = t2;
  const int b = mgrp*16 + (lane & 15);
  const int tok = que[b*S_ + t];
  const int k0 = kc*32 + (lane >> 4)*8;
  unsigned short* dst = px + (size_t)i*8;
  #pragma unroll
  for (int j = 0; j < 8; ++j){
    int k = k0 + j;
    dst[j] = (tok == 0 || k >= 300) ? (unsigned short)0 : f2bf(emb[(size_t)tok*300 + k]);
  }
}

// ---------------- x-part GEMM for all steps -> xg (fragment-order bf16) -------
__launch_bounds__(256, 4)
__global__ void k_xg(const unsigned short* __restrict__ px,
                     const unsigned short* __restrict__ pkW2,
                     unsigned short* __restrict__ xg){
  const int dir = blockIdx.x >> 5, uslab = blockIdx.x & 31;
  const int mslab = blockIdx.y;
  const int xs = blockIdx.z;
  const int tid = threadIdx.x, w = tid >> 6, lane = tid & 63;

  const unsigned short* pb = pkW2 + ((((size_t)(dir*32 + uslab)*4 + w)*2)*KC*64 + lane)*8;
  const size_t pbPair = (size_t)KC*512;
  const unsigned short* pax = px + (((size_t)(xs*8 + mslab*2)*12)*64 + lane)*8;
  const size_t paxRf = (size_t)12*512;

  f32x4 a00{0,0,0,0}, a01{0,0,0,0}, a10{0,0,0,0}, a11{0,0,0,0};
  #pragma unroll 4
  for (int ch = 0; ch < 12; ++ch){
    short8v a0 = *(const short8v*)(pax + (size_t)ch*512);
    short8v a1 = *(const short8v*)(pax + paxRf + (size_t)ch*512);
    short8v b0 = *(const short8v*)(pb + (size_t)ch*512);
    short8v b1 = *(const short8v*)(pb + pbPair + (size_t)ch*512);
    a00 = MFMA16(a0, b0, a00); a01 = MFMA16(a0, b1, a01);
    a10 = MFMA16(a1, b0, a10); a11 = MFMA16(a1, b1, a11);
  }

  const size_t rid = (((size_t)((xs*2 + dir)*4 + mslab)*32 + uslab)*4 + w);
  unsigned short* rec = xg + rid*1024;
  f32x4 accs[4] = {a00, a01, a10, a11};
  #pragma unroll
  for (int r = 0; r < 2; ++r)
    #pragma unroll
    for (int p = 0; p < 2; ++p){
      f32x4 v = accs[r*2 + p];
      short4v sv;
      #pragma unroll
      for (int j = 0; j < 4; ++j) sv[j] = (short)f2bf(v[j]);
      *(short4v*)(rec + ((p*2 + r)*64 + lane)*4) = sv;
    }
}

// ---------------- conv3 weights -> fragment-order pack ------------------------
__global__ void k_packC(const float* __restrict__ w, unsigned short* __restrict__ pk,
                        int cin, int T){
  int i = blockIdx.x*256 + threadIdx.x;
  if (i >= 9*8*T*64) return;
  const int lane = i & 63;
  int t = i >> 6;
  const int kc = t % T; t /= T;
  const int ot = t % 8; t /= 8;
  const int s = t;
  const int oc = ot*16 + (lane & 15);
  const int c0 = kc*32 + (lane >> 4)*8;
  unsigned short* dst = pk + (((size_t)(s*8 + ot)*T + kc)*64 + lane)*8;
  #pragma unroll
  for (int j = 0; j < 8; ++j){
    int c = c0 + j;
    dst[j] = (c < cin) ? f2bf(w[((size_t)oc*cin + c)*9 + s]) : (unsigned short)0;
  }
}

// ---------------- 1x1 weights [128][cin] -> fragment-order pack ---------------
__global__ void k_packG(const float* __restrict__ w, unsigned short* __restrict__ pk,
                        int cin, int T){
  int i = blockIdx.x*256 + threadIdx.x;
  if (i >= 8*T*64) return;
  const int lane = i & 63;
  int t = i >> 6;
  const int kc = t % T; t /= T;
  const int ot = t;
  const int oc = ot*16 + (lane & 15);
  const int c0 = kc*32 + (lane >> 4)*8;
  unsigned short* dst = pk + (((size_t)(ot*T + kc))*64 + lane)*8;
  #pragma unroll
  for (int j = 0; j < 8; ++j){
    int c = c0 + j;
    dst[j] = (c < cin) ? f2bf(w[(size_t)oc*cin + c]) : (unsigned short)0;
  }
}

__global__ void k_bias2(const float* __restrict__ bif, const float* __restrict__ bhf,
                        const float* __restrict__ bib, const float* __restrict__ bhb,
                        float* __restrict__ out){
  int i = blockIdx.x*256 + threadIdx.x;
  if (i >= 8192) return;
  out[i] = (i < 4096) ? (bif[i] + bhf[i]) : (bib[i-4096] + bhb[i-4096]);
}

// ---------------- vTb coord channels (written once) ---------------------------
__global__ void k_coordT(unsigned short* __restrict__ outT){
  int i = blockIdx.x*256 + threadIdx.x;
  if (i >= 128*196*32) return;
  int c2 = i & 31; int t = i >> 5; int p = t % 196; int b = t / 196;
  float v = (c2 == 0) ? c0f(p) : (c2 == 1) ? c1f(p) : 0.f;
  outT[((size_t)b*196 + p)*160 + 128 + c2] = f2bf(v);
}

// ---------------- one LSTM step (v11: M=16 rows, 4 blocks/CU) -----------------
__launch_bounds__(256, 4)
__global__ void k_step11(const unsigned short* __restrict__ xg,
                         const unsigned short* __restrict__ pkW2,
                         const float* __restrict__ bias2,
                         const unsigned short* __restrict__ hin,
                         unsigned short* __restrict__ hout,
                         float* __restrict__ cst, float* __restrict__ Q, int s){
  const int dir   = blockIdx.x >> 5;
  const int uslab = blockIdx.x & 31;
  const int mslab = blockIdx.y;          // 0..7, 16 rows each
  const int m0g   = mslab*16;
  const int tid = threadIdx.x, w = tid >> 6, lane = tid & 63;
  const int lr = lane & 15, lk = lane >> 4;
  const int xs = dir ? (S_-1-s) : s;

  __shared__ unsigned short tA[16][1032];

  {
    const int r = tid >> 4, sg = tid & 15;
    const unsigned short* hr = hin + ((size_t)dir*B_ + m0g + r)*H_;
    #pragma unroll
    for (int q = 0; q < 8; ++q){
      const int u = sg + q*16;
      *(short8v*)&tA[r][u*8] = *(const short8v*)(hr + u*8);
    }
  }

  const size_t rid = (((size_t)((xs*2 + dir)*4 + (mslab >> 1))*32 + uslab)*4 + w);
  const int rf = mslab & 1;
  const unsigned short* rec = xg + rid*1024;
  f32x4 a00, a01;
  {
    short4v s0 = *(const short4v*)(rec + ((0*2 + rf)*64 + lane)*4);
    short4v s1 = *(const short4v*)(rec + ((1*2 + rf)*64 + lane)*4);
    #pragma unroll
    for (int j = 0; j < 4; ++j){
      a00[j] = bf2f((unsigned short)s0[j]);
      a01[j] = bf2f((unsigned short)s1[j]);
    }
  }

  const unsigned short* pb = pkW2 + ((((size_t)(dir*32 + uslab)*4 + w)*2)*KC*64 + lane)*8;
  const size_t pbPair = (size_t)KC*512;

  __syncthreads();

  #pragma unroll 8
  for (int ch = 0; ch < 32; ++ch){
    const int ka = ch*32 + lk*8;
    short8v a0 = *(short8v*)&tA[lr][ka];
    short8v b0 = *(const short8v*)(pb + (size_t)(12 + ch)*512);
    short8v b1 = *(const short8v*)(pb + pbPair + (size_t)(12 + ch)*512);
    a00 = MFMA16(a0, b0, a00);
    a01 = MFMA16(a0, b1, a01);
  }

  const int ug = uslab*32 + w*8 + (lr & 7);
  const float* bb = bias2 + (size_t)dir*4096;
  const float bi = bb[ug], bfv = bb[1024+ug], bg = bb[2048+ug], bo = bb[3072+ug];
  float* cc = cst + (size_t)dir*B_*H_;
  unsigned short* ho = hout + (size_t)dir*B_*H_;
  const int jbase = (lr & 8) ? 2 : 0;

  float p0[4], p1[4];
  #pragma unroll
  for (int j = 0; j < 4; ++j){
    p0[j] = __shfl_xor(a00[j], 8, 64);
    p1[j] = __shfl_xor(a01[j], 8, 64);
  }
  #pragma unroll
  for (int q = 0; q < 2; ++q){
    const int jj = jbase + q;
    float gi, gf, gg, go;
    if (lr & 8){ gi = p0[jj]; gf = a00[jj]; gg = p1[jj]; go = a01[jj]; }
    else       { gi = a00[jj]; gf = p0[jj]; gg = a01[jj]; go = p1[jj]; }
    gi += bi; gf += bfv; gg += bg; go += bo;
    const int m = m0g + lk*4 + jj;
    const size_t coff = (size_t)m*H_ + ug;
    float cold = cc[coff];
    float cn = sigm(gf)*cold + sigm(gi)*tanhf(gg);
    float hn = sigm(go)*tanhf(cn);
    cc[coff] = cn;
    ho[coff] = f2bf(hn);
    Q[((size_t)xs*B_ + m)*2048 + dir*1024 + ug] = hn;
  }
}

// ---------------- qenc L2-normalize (in-place) + enc --------------------------
__global__ void k_qnorm(float* __restrict__ Q, float* __restrict__ enc){
  int sb = blockIdx.x;
  int s = sb >> 7, b = sb & 127;
  float* row = Q + (size_t)sb*2048;
  int tid = threadIdx.x;
  float v[8]; float ss = 0.f;
  #pragma unroll
  for (int i = 0; i < 8; ++i){ v[i] = row[tid*8+i]; ss += v[i]*v[i]; }
  __shared__ float red[256];
  red[tid] = ss; __syncthreads();
  for (int st = 128; st; st >>= 1){
    if (tid < st) red[tid] += red[tid+st];
    __syncthreads();
  }
  float inv = 1.0f / fmaxf(sqrtf(red[0]), 1e-12f);
  #pragma unroll
  for (int i = 0; i < 8; ++i){
    float q = v[i]*inv;
    row[tid*8+i] = q;
    if (s == S_-1) enc[(size_t)b*2048 + tid*8 + i] = q;
  }
}

// ---------------- per-pixel channel sumsq of img ------------------------------
__global__ void k_sqpart(const float* __restrict__ img, float* __restrict__ part){
  int b = blockIdx.x, cq = blockIdx.y;
  int t = threadIdx.x;
  if (t >= P_) return;
  const float* base = img + ((size_t)b*1024 + cq*256)*P_ + t;
  float s = 0.f;
  #pragma unroll 4
  for (int c = 0; c < 256; ++c){ float v = base[c*P_]; s += v*v; }
  part[((size_t)b*4 + cq)*P_ + t] = s;
}

__global__ void k_invnorm(const float* __restrict__ part, float* __restrict__ inv){
  int i = blockIdx.x*256 + threadIdx.x;
  if (i >= B_*P_) return;
  int b = i / P_, p = i % P_;
  float s = part[(b*4+0)*P_+p] + part[(b*4+1)*P_+p]
          + part[(b*4+2)*P_+p] + part[(b*4+3)*P_+p];
  inv[i] = 1.0f / fmaxf(sqrtf(s), 1e-12f);
}

// ---------------- img -> imgT[b][196][1056] bf16 (invnorm+coords+pad) ---------
__global__ void k_mkimgT(const float* __restrict__ img, const float* __restrict__ invn,
                         unsigned short* __restrict__ imgT){
  const int b = blockIdx.x, cg = blockIdx.y;
  const int tid = threadIdx.x;
  unsigned short* dstB = imgT + (size_t)b*196*1056;
  if (cg == 8){
    for (int i = tid; i < 196*32; i += 256){
      int p = i >> 5, cc = i & 31;
      float v = (cc == 0) ? c0f(p) : (cc == 1) ? c1f(p) : 0.f;
      dstB[(size_t)p*1056 + 1024 + cc] = f2bf(v);
    }
    return;
  }
  __shared__ unsigned short tt[196][136];
  __shared__ float sInv[200];
  for (int i = tid; i < 196; i += 256) sInv[i] = invn[b*196 + i];
  __syncthreads();
  const int c0 = cg*128;
  const float* srcB = img + ((size_t)b*1024 + c0)*196;
  for (int i = tid; i < 128*49; i += 256){
    int c = i / 49, p4 = i - (i/49)*49;
    float4 v = *(const float4*)(srcB + (size_t)c*196 + p4*4);
    int p = p4*4;
    tt[p+0][c] = f2bf(v.x * sInv[p+0]);
    tt[p+1][c] = f2bf(v.y * sInv[p+1]);
    tt[p+2][c] = f2bf(v.z * sInv[p+2]);
    tt[p+3][c] = f2bf(v.w * sInv[p+3]);
  }
  __syncthreads();
  for (int i = tid; i < 196*16; i += 256){
    int p = i >> 4, g = i & 15;
    *(short8v*)(dstB + (size_t)p*1056 + c0 + g*8) = *(short8v*)&tt[p][g*8];
  }
}

// ---------------- shared staging helper ---------------------------------------
template<int CPAD>
__device__ __forceinline__ void stage3t(unsigned short (*__restrict__ tile)[40],
                                        const unsigned short* __restrict__ src,
                                        int c0, int r0, int tid){
  for (int i = tid; i < 10*14*4; i += 256){
    int t = i / 56, rem = i - t*56, gx = rem >> 2, seg = rem & 3;
    int gy = r0 - 1 + t;
    if ((unsigned)gy < 14u){
      short8v v = *(const short8v*)(src + (size_t)(gy*14+gx)*CPAD + c0 + seg*8);
      *(short8v*)&tile[t*16 + gx + 1][seg*8] = v;
    }
  }
}

// ---------------- 3x3 conv via MFMA (proven z2 template) ----------------------
template<int CPAD>
__launch_bounds__(256, 2)
__global__ void k_conv3t(const unsigned short* __restrict__ srcT,
                         const unsigned short* __restrict__ wPk,
                         const float* __restrict__ bias,
                         float* __restrict__ out){
  constexpr int T = CPAD / 32;
  const int b = blockIdx.x, n = blockIdx.y, z = blockIdx.z;
  const int r0 = n ? 6 : 0;
  const int chBeg = z ? T/2 : 0, chEnd = z ? T : T/2;
  const int tid = threadIdx.x, wave = tid >> 6, lane = tid & 63;
  const int lr = lane & 15, lk = lane >> 4;
  const int wfM = wave >> 1, wfN = wave & 1;
  const unsigned short* src = srcT + (size_t)b*196*CPAD;

  __shared__ unsigned short tile[2][164][40];

  for (int i = tid; i < 1640; i += 256)
    ((short8v*)&tile[0][0][0])[i] = short8v{0,0,0,0,0,0,0,0};
  __syncthreads();
  stage3t<CPAD>(tile[0], src, chBeg*32, r0, tid);
  __syncthreads();

  f32x4 acc[4][4];
  #pragma unroll
  for (int i = 0; i < 4; ++i)
    #pragma unroll
    for (int j = 0; j < 4; ++j) acc[i][j] = f32x4{0,0,0,0};

  short8v aC[12], aN[12];
  #pragma unroll
  for (int dx = 0; dx < 3; ++dx)
    #pragma unroll
    for (int rf = 0; rf < 4; ++rf)
      aC[dx*4+rf] = *(const short8v*)(wPk + ((((size_t)dx*8 + wfM*4 + rf)*T + chBeg)*64
                                             + lane)*8);

  for (int ch = chBeg; ch < chEnd; ++ch){
    const int cur = (ch - chBeg) & 1;
    #pragma unroll
    for (int dy = 0; dy < 3; ++dy){
      const int ndy = (dy < 2) ? dy + 1 : 0;
      const int nch = (dy < 2) ? ch : ch + 1;
      const bool hasN = nch < chEnd;
      if (hasN){
        #pragma unroll
        for (int dx = 0; dx < 3; ++dx)
          #pragma unroll
          for (int rf = 0; rf < 4; ++rf)
            aN[dx*4+rf] = *(const short8v*)(wPk + ((((size_t)(ndy*3+dx)*8 + wfM*4 + rf)*T
                                                    + nch)*64 + lane)*8);
      }
      #pragma unroll
      for (int dx = 0; dx < 3; ++dx){
        const int dlt = dy*16 + dx;
        #pragma unroll
        for (int cf = 0; cf < 4; ++cf){
          short8v bf = *(short8v*)&tile[cur][wfN*64 + cf*16 + lr + dlt][lk*8];
          #pragma unroll
          for (int rf = 0; rf < 4; ++rf)
            acc[rf][cf] = MFMA16(aC[dx*4+rf], bf, acc[rf][cf]);
        }
      }
      if (dy == 0 && ch + 1 < chEnd)
        stage3t<CPAD>(tile[cur^1], src, (ch+1)*32, r0, tid);
      if (hasN){
        #pragma unroll
        for (int q = 0; q < 12; ++q) aC[q] = aN[q];
      }
    }
    __syncthreads();
  }

  #pragma unroll
  for (int rf = 0; rf < 4; ++rf){
    #pragma unroll
    for (int j = 0; j < 4; ++j){
      const int oc = wfM*64 + rf*16 + lk*4 + j;
      const float bz = z ? 0.f : bias[oc];
      #pragma unroll
      for (int cf = 0; cf < 4; ++cf){
        const int pos = wfN*64 + cf*16 + lr;
        const int py = r0 + (pos >> 4), px = pos & 15;
        const bool rowok = n ? (py >= 8) : true;
        if (rowok && px < 14)
          out[(size_t)z*NE + ((size_t)b*OC_ + oc)*P_ + py*14 + px] = acc[rf][cf][j] + bz;
      }
    }
  }
}

// ---------------- BN stats: phase 1 (partials over 2 slabs) -------------------
__global__ void k_bnstats2(const float* __restrict__ t, float* __restrict__ bpart){
  const int o = blockIdx.x, part = blockIdx.y;
  const int tid = threadIdx.x;
  float s = 0.f, s2 = 0.f;
  for (int i = tid; i < 16*196; i += 256){
    int b = part*16 + i/196, p = i - (i/196)*196;
    size_t off = ((size_t)b*OC_ + o)*P_ + p;
    float v = t[off] + t[off + NE];
    s += v; s2 += v*v;
  }
  __shared__ float r1[256], r2[256];
  r1[tid] = s; r2[tid] = s2; __syncthreads();
  for (int st = 128; st; st >>= 1){
    if (tid < st){ r1[tid] += r1[tid+st]; r2[tid] += r2[tid+st]; }
    __syncthreads();
  }
  if (tid == 0){
    bpart[(o*8 + part)*2]     = r1[0];
    bpart[(o*8 + part)*2 + 1] = r2[0];
  }
}

// ---------------- BN apply + relu (+add), inline stats finalize ---------------
// grid (128 b, 8 seg). Each block folds the 8 bpart partials for its 16
// channels (replaces the separate k_bnfin launch).
template<bool ADD, bool FINAL>
__global__ void k_bntr(const float* __restrict__ t, const float* __restrict__ bpart,
                       const float* __restrict__ g, const float* __restrict__ bb,
                       const float* __restrict__ addsrc,
                       float* __restrict__ outF, unsigned short* __restrict__ outT){
  const int b = blockIdx.x, seg = blockIdx.y, tid = threadIdx.x;
  __shared__ float sM[16], sI[16];
  if (tid < 16){
    const int c = seg*16 + tid;
    float s = 0.f, s2 = 0.f;
    #pragma unroll
    for (int q = 0; q < 8; ++q){
      s  += bpart[(c*8 + q)*2];
      s2 += bpart[(c*8 + q)*2 + 1];
    }
    const float n = (float)(B_*P_);
    const float m = s / n;
    sM[tid] = m;
    sI[tid] = rsqrtf(s2 / n - m*m + 1e-5f);
  }
  __syncthreads();
  for (int i = tid; i < 16*196; i += 256){
    int cl = i/196, p = i - cl*196;
    int c = seg*16 + cl;
    size_t off = ((size_t)b*OC_ + c)*P_ + p;
    float x = t[off] + t[off + NE];
    float v = g[c]*(x - sM[cl])*sI[cl] + bb[c];
    v = fmaxf(v, 0.f);
    if (ADD) v += addsrc[off];
    if (FINAL) outF[off] = v;
    else       outT[((size_t)b*P_ + p)*160 + c] = f2bf(v);
  }
}

// ---------------- 1x1 conv via MFMA -------------------------------------------
__launch_bounds__(256, 2)
__global__ void k_c1m(const unsigned short* __restrict__ vT,
                      const unsigned short* __restrict__ pk,
                      const float* __restrict__ bias,
                      float* __restrict__ out, unsigned short* __restrict__ outT){
  const int b = blockIdx.x, n = blockIdx.y;
  const int pBeg = n ? 112 : 0;
  const int nCF = n ? 6 : 7;
  const int tid = threadIdx.x, wave = tid >> 6, lane = tid & 63;
  const int lr = lane & 15, lk = lane >> 4;

  __shared__ unsigned short tile[112][164];

  for (int i = tid; i < 112*20; i += 256){
    int r = i / 20, seg = i - r*20;
    int p = pBeg + r;
    short8v v = short8v{0,0,0,0,0,0,0,0};
    if (p < 196 && r < nCF*16)
      v = *(const short8v*)(vT + ((size_t)b*P_ + p)*160 + seg*8);
    *(short8v*)&tile[r][seg*8] = v;
  }
  __syncthreads();

  f32x4 acc[2][7];
  #pragma unroll
  for (int i = 0; i < 2; ++i)
    #pragma unroll
    for (int j = 0; j < 7; ++j) acc[i][j] = f32x4{0,0,0,0};

  #pragma unroll
  for (int kc = 0; kc < 5; ++kc){
    short8v a0 = *(const short8v*)(pk + (((size_t)(wave*2 + 0)*5 + kc)*64 + lane)*8);
    short8v a1 = *(const short8v*)(pk + (((size_t)(wave*2 + 1)*5 + kc)*64 + lane)*8);
    #pragma unroll
    for (int cf = 0; cf < 7; ++cf){
      if (cf < nCF){
        short8v bf = *(short8v*)&tile[cf*16 + lr][kc*32 + lk*8];
        acc[0][cf] = MFMA16(a0, bf, acc[0][cf]);
        acc[1][cf] = MFMA16(a1, bf, acc[1][cf]);
      }
    }
  }

  #pragma unroll
  for (int rf = 0; rf < 2; ++rf){
    const int ocBase = wave*32 + rf*16 + lk*4;
    #pragma unroll
    for (int cf = 0; cf < 7; ++cf){
      if (cf < nCF){
        const int pos = pBeg + cf*16 + lr;
        if (pos < 196){
          short4v sv;
          #pragma unroll
          for (int j = 0; j < 4; ++j){
            const int oc = ocBase + j;
            float v = fmaxf(acc[rf][cf][j] + bias[oc], 0.f);
            out[((size_t)b*OC_ + oc)*P_ + pos] = v;
            sv[j] = (short)f2bf(v);
          }
          *(short4v*)(outT + ((size_t)b*P_ + pos)*128 + ocBase) = sv;
        }
      }
    }
  }
}

} // namespace

// ---------------------------------------------------------------------------
extern "C" void kernel_launch(void* const* d_in, const int* in_sizes, int n_in,
                              void* d_out, int out_size, void* d_ws, size_t ws_size,
                              hipStream_t stream){
  (void)in_sizes; (void)n_in; (void)out_size; (void)ws_size;
  const int*   que  = (const int*)  d_in[0];
  const float* img  = (const float*)d_in[1];
  const float* emb  = (const float*)d_in[2];
  const float* wihf = (const float*)d_in[3];
  const float* whhf = (const float*)d_in[4];
  const float* bihf = (const float*)d_in[5];
  const float* bhhf = (const float*)d_in[6];
  const float* wihb = (const float*)d_in[7];
  const float* whhb = (const float*)d_in[8];
  const float* bihb = (const float*)d_in[9];
  const float* bhhb = (const float*)d_in[10];
  const float* convw = (const float*)d_in[11];
  const float* convb = (const float*)d_in[12];
  const float* bng  = (const float*)d_in[13];
  const float* bnb  = (const float*)d_in[14];
  const float* r1c1w = (const float*)d_in[15];
  const float* r1c1b = (const float*)d_in[16];
  const float* r1c2w = (const float*)d_in[17];
  const float* r1c2b = (const float*)d_in[18];
  const float* r1bng = (const float*)d_in[19];
  const float* r1bnb = (const float*)d_in[20];
  const float* r2c1w = (const float*)d_in[21];
  const float* r2c1b = (const float*)d_in[22];
  const float* r2c2w = (const float*)d_in[23];
  const float* r2c2b = (const float*)d_in[24];
  const float* r2bng = (const float*)d_in[25];
  const float* r2bnb = (const float*)d_in[26];

  float* out  = (float*)d_out;
  float* enc  = out;                        // 128*2048
  float* Q    = out + 262144;               // 32*128*2048
  float* vout = out + 262144 + 8388608;     // 128*128*196

  // ------ workspace layout (f32 units) ----------------------------------------
  float* ws = (float*)d_ws;
  unsigned short* px   = (unsigned short*)ws;                  // 32*8*12*512 bf16
  unsigned short* pkW2 = (unsigned short*)(ws + 786432);       // 2*32*4*2*44*512 bf16
  float* bias2 = ws + 6553600;                                 // 2*4096
  unsigned short* hstate = (unsigned short*)(ws + 6561792);    // 2par*2dir*128*1024 bf16
  float* cstate = ws + 6823936;                                // 2*128*1024
  float* part   = ws + 7086080;                                // 128*4*196
  float* invn   = ws + 7186432;                                // 128*196
  float* bpart  = ws + 7211520;                                // 128*8*2
  unsigned short* pkC  = (unsigned short*)(ws + 7213824);      // 9*8*33*512 bf16
  unsigned short* pkR1 = (unsigned short*)(ws + 7822080);      // 9*8*4*512 bf16
  unsigned short* pkR2 = (unsigned short*)(ws + 7895808);      // 9*8*4*512 bf16
  unsigned short* pk1  = (unsigned short*)(ws + 7969536);      // 8*5*512 bf16
  unsigned short* pk2  = (unsigned short*)(ws + 7979776);      // 8*5*512 bf16
  float* U = ws + 7990016;                                     // union region
  // LSTM phase: xg = 32768 records x 1024 bf16 = 16.8M floats
  unsigned short* xg = (unsigned short*)U;
  // image phase (bufB/convOut/imgT written only after LSTM finishes):
  float* bufB = U;                                             // NE (v1 f32)
  float* convOut = U + NE;                                     // 2*NE partial slabs
  unsigned short* imgT = (unsigned short*)(U + 3*(size_t)NE);  // 128*196*1056
  unsigned short* vTb  = (unsigned short*)(U + 3*(size_t)NE + 13246464);
  unsigned short* v1T  = (unsigned short*)(U + 3*(size_t)NE + 13246464 + 2007040);

  hipMemsetAsync(hstate, 0, (size_t)(262144 + 262144)*sizeof(float), stream);

  // ------ packing / conversions ------------------------------------------------
  k_packW2<<<(2*32*4*2*KC*64 + 255)/256, 256, 0, stream>>>(wihf, whhf, wihb, whhb, pkW2);
  k_embed_px<<<(32*8*12*64 + 255)/256, 256, 0, stream>>>(que, emb, px);
  k_packC<<<(9*8*33*64 + 255)/256, 256, 0, stream>>>(convw, pkC, 1026, 33);
  k_packC<<<(9*8*4*64 + 255)/256, 256, 0, stream>>>(r1c2w, pkR1, 128, 4);
  k_packC<<<(9*8*4*64 + 255)/256, 256, 0, stream>>>(r2c2w, pkR2, 128, 4);
  k_packG<<<(8*5*64 + 255)/256, 256, 0, stream>>>(r1c1w, pk1, 130, 5);
  k_packG<<<(8*5*64 + 255)/256, 256, 0, stream>>>(r2c1w, pk2, 130, 5);
  k_bias2<<<32, 256, 0, stream>>>(bihf, bhhf, bihb, bhhb, bias2);
  k_coordT<<<(128*196*32 + 255)/256, 256, 0, stream>>>(vTb);   // vTb doesn't alias xg

  // ------ x-part GEMM for all steps (one wide launch) --------------------------
  k_xg<<<dim3(64,4,32), 256, 0, stream>>>(px, pkW2, xg);

  // ------ bi-LSTM: 32 h-only step launches (M=16 rows/block) -------------------
  for (int s = 0; s < 32; ++s){
    unsigned short* hin  = hstate + (size_t)(s & 1)*262144;
    unsigned short* hout = hstate + (size_t)((s & 1)^1)*262144;
    k_step11<<<dim3(64,8), 256, 0, stream>>>(xg, pkW2, bias2, hin, hout,
                                             cstate, Q, s);
  }
  k_qnorm<<<4096, 256, 0, stream>>>(Q, enc);

  // ------ image branch (after LSTM: imgT/bufB/convOut alias xg) ---------------
  k_sqpart<<<dim3(128,4), 256, 0, stream>>>(img, part);
  k_invnorm<<<(25088+255)/256, 256, 0, stream>>>(part, invn);
  k_mkimgT<<<dim3(128,9), 256, 0, stream>>>(img, invn, imgT);

  k_conv3t<1056><<<dim3(128,2,2), 256, 0, stream>>>(imgT, pkC, convb, convOut);
  k_bnstats2<<<dim3(128,8), 256, 0, stream>>>(convOut, bpart);
  k_bntr<false,false><<<dim3(128,8), 256, 0, stream>>>(convOut, bpart, bng, bnb,
                                                       nullptr, nullptr, vTb);

  // res block 1: vTb -> (bufB f32, v1T) -> convOut -> vTb
  k_c1m<<<dim3(128,2), 256, 0, stream>>>(vTb, pk1, r1c1b, bufB, v1T);
  k_conv3t<128><<<dim3(128,2,2), 256, 0, stream>>>(v1T, pkR1, r1c2b, convOut);
  k_bnstats2<<<dim3(128,8), 256, 0, stream>>>(convOut, bpart);
  k_bntr<true,false><<<dim3(128,8), 256, 0, stream>>>(convOut, bpart, r1bng, r1bnb,
                                                      bufB, nullptr, vTb);

  // res block 2: vTb -> (bufB, v1T) -> convOut -> vout
  k_c1m<<<dim3(128,2), 256, 0, stream>>>(vTb, pk2, r2c1b, bufB, v1T);
  k_conv3t<128><<<dim3(128,2,2), 256, 0, stream>>>(v1T, pkR2, r2c2b, convOut);
  k_bnstats2<<<dim3(128,8), 256, 0, stream>>>(convOut, bpart);
  k_bntr<true,true><<<dim3(128,8), 256, 0, stream>>>(convOut, bpart, r2bng, r2bnb,
                                                     bufB, vout, nullptr);
}